// Round 2
// baseline (406.708 us; speedup 1.0000x reference)
//
#include <hip/hip_runtime.h>
#include <math.h>

#define BB 32
#define DD 64
#define LL 8192
#define KK 512
#define NN (BB*LL)                 // 262144 rows

#define OUT0_SZ  (BB*DD*LL)        // 16777216
#define LOSS_OFF (OUT0_SZ)         // 16777216
#define PERP_OFF (OUT0_SZ + 1)     // 16777217
#define W_OFF    (OUT0_SZ + 2)     // 16777218
#define IDX_OFF  (W_OFF + KK*DD)   // 16809986

// ws layout: float t[512] | int hist[512] | float loss_acc
// -----------------------------------------------------------------------------
// init: t_k = ||w_k||^2 in numpy-pairwise(unroll-8) fp32 order; zero hist/loss
__global__ void vq_init(const float* __restrict__ w, float* __restrict__ tvec,
                        int* __restrict__ hist, float* __restrict__ lacc) {
#pragma clang fp contract(off)
  int k = blockIdx.x * blockDim.x + threadIdx.x;
  if (k < KK) {
    const float* wr = w + k * DD;
    float r[8];
#pragma unroll
    for (int j = 0; j < 8; j++) { float v = wr[j]; r[j] = v * v; }
#pragma unroll
    for (int blk = 8; blk < 64; blk += 8) {
#pragma unroll
      for (int j = 0; j < 8; j++) { float v = wr[blk + j]; float a = v * v; r[j] = r[j] + a; }
    }
    tvec[k] = ((r[0] + r[1]) + (r[2] + r[3])) + ((r[4] + r[5]) + (r[6] + r[7]));
    hist[k] = 0;
  }
  if (k == 0 && blockIdx.x == 0) *lacc = 0.0f;
}

// readlane broadcast: SGPR result, feeds v_fma as the (single allowed) scalar src
__device__ __forceinline__ float rlane(float v, int l) {
  return __uint_as_float(__builtin_amdgcn_readlane(__float_as_uint(v), l));
}

// -----------------------------------------------------------------------------
// main: 256 threads, 2 rows/thread, 512 rows/block, 512 blocks.
// w transport: per-lane coalesced VMEM load (lane d holds w[c][d], 8-code
// prefetch ring in VGPRs) + v_readlane broadcast into SGPRs for the fma.
// No SMEM in the loop (R0: ~1000 cyc/code scalar-cache stall), no LDS
// replication (R-1: 12 cyc/b128 broadcast return BW). Pure VALU steady state.
__launch_bounds__(256, 2)
__global__ void vq_main(const float* __restrict__ x, const float* __restrict__ w,
                        const float* __restrict__ tvec, int* __restrict__ hist,
                        float* __restrict__ lacc, float* __restrict__ dout) {
#pragma clang fp contract(off)
  __shared__ unsigned char flags[KK];
  __shared__ float t_lds[KK];

  const int tid = threadIdx.x;
  for (int e = tid; e < KK; e += 256) { flags[e] = 0; t_lds[e] = tvec[e]; }

  const int n0 = blockIdx.x * 512 + tid;
  const int n1 = n0 + 256;
  const int b0 = n0 >> 13, l0 = n0 & 8191;
  const int b1 = n1 >> 13, l1 = n1 & 8191;
  const float* p0 = x + (size_t)b0 * DD * LL + l0;
  const float* p1 = x + (size_t)b1 * DD * LL + l1;

  float x0[64], x1[64];
#pragma unroll
  for (int i = 0; i < 64; i++) { x0[i] = p0[(size_t)i * LL]; x1[i] = p1[(size_t)i * LL]; }

  // s = ||x||^2, numpy-pairwise order (precision non-critical: uniform shift)
  float s0, s1;
  {
    float r0[8], r1[8];
#pragma unroll
    for (int j = 0; j < 8; j++) { r0[j] = x0[j] * x0[j]; r1[j] = x1[j] * x1[j]; }
#pragma unroll
    for (int blk = 8; blk < 64; blk += 8) {
#pragma unroll
      for (int j = 0; j < 8; j++) {
        float a0 = x0[blk + j] * x0[blk + j]; r0[j] = r0[j] + a0;
        float a1 = x1[blk + j] * x1[blk + j]; r1[j] = r1[j] + a1;
      }
    }
    s0 = ((r0[0] + r0[1]) + (r0[2] + r0[3])) + ((r0[4] + r0[5]) + (r0[6] + r0[7]));
    s1 = ((r1[0] + r1[1]) + (r1[2] + r1[3])) + ((r1[4] + r1[5]) + (r1[6] + r1[7]));
  }

  // per-lane w stream: lane d reads w[c][d]; 8-deep static-index prefetch ring
  const int lane = tid & 63;
  const float* wl = w + lane;
  float wbuf[8];
#pragma unroll
  for (int j = 0; j < 8; j++) wbuf[j] = wl[j * DD];

  __syncthreads();   // flags zeroed + t_lds populated before loop & post-loop use

  float dmin0 = INFINITY, dmin1 = INFINITY;
  int   k0 = 0, k1 = 0;

#pragma clang loop unroll(disable)
  for (int cg = 0; cg < KK; cg += 8) {
#pragma unroll
    for (int j = 0; j < 8; j++) {
      const int c = cg + j;
      const float wv = wbuf[j];
      // refill ring for c+8 (wraps at 512: harmless re-read, branch-free)
      wbuf[j] = wl[((c + 8) & (KK - 1)) * DD];
      const float tc = t_lds[c];

      // Exact same fma chain order as prior verified kernels: d = 0..63
      // sequential, g starts at 0, independent g0/g1 chains interleaved.
      float g0 = 0.0f, g1 = 0.0f;
#pragma unroll
      for (int dd = 0; dd < 64; dd += 4) {
        const float b0v = rlane(wv, dd + 0);
        const float b1v = rlane(wv, dd + 1);
        const float b2v = rlane(wv, dd + 2);
        const float b3v = rlane(wv, dd + 3);
        g0 = fmaf(x0[dd + 0], b0v, g0); g1 = fmaf(x1[dd + 0], b0v, g1);
        g0 = fmaf(x0[dd + 1], b1v, g0); g1 = fmaf(x1[dd + 1], b1v, g1);
        g0 = fmaf(x0[dd + 2], b2v, g0); g1 = fmaf(x1[dd + 2], b2v, g1);
        g0 = fmaf(x0[dd + 3], b3v, g0); g1 = fmaf(x1[dd + 3], b3v, g1);
      }

      float u0 = s0 + tc;                 // fl32(s + t_k) — matches np broadcast add
      float u1 = s1 + tc;
      float d0 = fmaf(-2.0f, g0, u0);     // fl32(u - 2g), 2g exact
      float d1 = fmaf(-2.0f, g1, u1);
      if (d0 < dmin0) { dmin0 = d0; k0 = c; }   // strict <: first index on tie
      if (d1 < dmin1) { dmin1 = d1; k1 = c; }
    }
  }

  // epilogue: quantized output (transposed back), loss partial, idx, flags
  float ls = 0.0f;
  {
    float* o0 = dout + (size_t)b0 * DD * LL + l0;
    const float4* wr = (const float4*)(w + k0 * DD);
#pragma unroll
    for (int i = 0; i < 16; i++) {
      float4 v = wr[i];
      o0[(size_t)(4*i+0) * LL] = v.x; o0[(size_t)(4*i+1) * LL] = v.y;
      o0[(size_t)(4*i+2) * LL] = v.z; o0[(size_t)(4*i+3) * LL] = v.w;
      float df;
      df = v.x - x0[4*i+0]; ls = fmaf(df, df, ls);
      df = v.y - x0[4*i+1]; ls = fmaf(df, df, ls);
      df = v.z - x0[4*i+2]; ls = fmaf(df, df, ls);
      df = v.w - x0[4*i+3]; ls = fmaf(df, df, ls);
    }
  }
  {
    float* o1 = dout + (size_t)b1 * DD * LL + l1;
    const float4* wr = (const float4*)(w + k1 * DD);
#pragma unroll
    for (int i = 0; i < 16; i++) {
      float4 v = wr[i];
      o1[(size_t)(4*i+0) * LL] = v.x; o1[(size_t)(4*i+1) * LL] = v.y;
      o1[(size_t)(4*i+2) * LL] = v.z; o1[(size_t)(4*i+3) * LL] = v.w;
      float df;
      df = v.x - x1[4*i+0]; ls = fmaf(df, df, ls);
      df = v.y - x1[4*i+1]; ls = fmaf(df, df, ls);
      df = v.z - x1[4*i+2]; ls = fmaf(df, df, ls);
      df = v.w - x1[4*i+3]; ls = fmaf(df, df, ls);
    }
  }
  dout[IDX_OFF + n0] = (float)k0;
  dout[IDX_OFF + n1] = (float)k1;

  // loss: wave reduce then one atomic per wave (threshold is huge; order-insensitive)
#pragma unroll
  for (int o = 32; o > 0; o >>= 1) ls += __shfl_down(ls, o);
  if ((tid & 63) == 0) atomicAdd(lacc, ls);

  // perplexity histogram: LDS filter then <=512 global atomics per block
  flags[k0] = 1; flags[k1] = 1;
  __syncthreads();
  for (int e = tid; e < KK; e += 256)
    if (flags[e]) atomicOr(&hist[e], 1);
}

// -----------------------------------------------------------------------------
// final: perplexity count, loss scalar, weight passthrough
__global__ void vq_final(const float* __restrict__ w, const int* __restrict__ hist,
                         const float* __restrict__ lacc, float* __restrict__ dout) {
  __shared__ int red[512];
  int tid = threadIdx.x;
  red[tid] = (hist[tid] != 0) ? 1 : 0;
  __syncthreads();
  for (int s = 256; s > 0; s >>= 1) {
    if (tid < s) red[tid] += red[tid + s];
    __syncthreads();
  }
  if (tid == 0) {
    dout[PERP_OFF] = (float)red[0];
    float m = *lacc / 16777216.0f;
    dout[LOSS_OFF] = m + 0.1f * m;   // q + 0.1*e with q==e numerically
  }
  // weight passthrough: W_OFF is 8B-aligned only -> float2 copies
  const float2* w2 = (const float2*)w;
  float2* o2 = (float2*)(dout + W_OFF);
  for (int j = tid; j < KK * DD / 2; j += 512) o2[j] = w2[j];
}

extern "C" void kernel_launch(void* const* d_in, const int* in_sizes, int n_in,
                              void* d_out, int out_size, void* d_ws, size_t ws_size,
                              hipStream_t stream) {
  const float* x = (const float*)d_in[0];
  const float* w = (const float*)d_in[1];
  float* dout = (float*)d_out;
  float* tvec = (float*)d_ws;
  int*   hist = (int*)d_ws + 512;
  float* lacc = (float*)d_ws + 1024;

  vq_init<<<2, 256, 0, stream>>>(w, tvec, hist, lacc);
  vq_main<<<NN / 512, 256, 0, stream>>>(x, w, tvec, hist, lacc, dout);
  vq_final<<<1, 512, 0, stream>>>(w, hist, lacc, dout);
}

// Round 3
// 245.962 us; speedup vs baseline: 1.6535x; 1.6535x over previous
//
#include <hip/hip_runtime.h>
#include <math.h>

#define BB 32
#define DD 64
#define LL 8192
#define KK 512
#define NN (BB*LL)                 // 262144 rows

#define OUT0_SZ  (BB*DD*LL)        // 16777216
#define LOSS_OFF (OUT0_SZ)
#define PERP_OFF (OUT0_SZ + 1)
#define W_OFF    (OUT0_SZ + 2)
#define IDX_OFF  (W_OFF + KK*DD)   // 16809986

// ws float-offsets: tvec[512] | hist[512] | lacc | pad | wpack_h (32768 u16) | wpack_l
#define WS_TVEC 0
#define WS_HIST 512
#define WS_LACC 1024
#define WS_WPH  1032
#define WS_WPL  (1032 + 16384)
// needs ws_size >= (1032+32768)*4 B ~= 133 KB

typedef __attribute__((ext_vector_type(4))) float f32x4;
typedef __attribute__((ext_vector_type(8))) short s16x8;

#define WINDOW 1e-4f   // covers 2*delta_apx(2.2e-5) + ref rounding wobble + 2 ulp(d) tie band

__device__ __forceinline__ unsigned short f2bf(float f) {   // RNE f32->bf16
  unsigned int u = __float_as_uint(f);
  return (unsigned short)((u + 0x7FFFu + ((u >> 16) & 1u)) >> 16);
}
__device__ __forceinline__ float bf2f(unsigned short s) {
  return __uint_as_float(((unsigned int)s) << 16);
}

// -----------------------------------------------------------------------------
// init (32768 threads): exact t_k (np-pairwise), zero hist/lacc, and pack the
// codebook as bf16 hi/lo in MFMA B-fragment order:
//   B elem (k,n) of tile ct,kstep -> lane = n + 16*(k/8), j = k%8
__global__ void vq_init(const float* __restrict__ w, float* __restrict__ ws) {
#pragma clang fp contract(off)
  int t = blockIdx.x * blockDim.x + threadIdx.x;
  if (t < KK) {
    const float* wr = w + t * DD;
    float r[8];
#pragma unroll
    for (int j = 0; j < 8; j++) { float v = wr[j]; r[j] = v * v; }
#pragma unroll
    for (int blk = 8; blk < 64; blk += 8) {
#pragma unroll
      for (int j = 0; j < 8; j++) { float v = wr[blk + j]; float a = v * v; r[j] = r[j] + a; }
    }
    ws[WS_TVEC + t] = ((r[0] + r[1]) + (r[2] + r[3])) + ((r[4] + r[5]) + (r[6] + r[7]));
    ((int*)ws)[WS_HIST + t] = 0;
  }
  if (t == 0) ws[WS_LACC] = 0.0f;

  int j    = t & 7;
  int lane = (t >> 3) & 63;
  int ks   = (t >> 9) & 1;
  int ct   = t >> 10;
  int code = ct * 16 + (lane & 15);
  int d    = ks * 32 + ((lane >> 4) << 3) + j;
  float v  = w[code * DD + d];
  unsigned short h = f2bf(v);
  unsigned short l = f2bf(v - bf2f(h));
  ((unsigned short*)(ws + WS_WPH))[((ct * 2 + ks) * 64 + lane) * 8 + j] = h;
  ((unsigned short*)(ws + WS_WPL))[((ct * 2 + ks) * 64 + lane) * 8 + j] = l;
}

// -----------------------------------------------------------------------------
// main: 1024 blocks x 256 threads; block owns 256 rows; wave owns 64 rows
// (4 MFMA row-tiles). 3-term bf16-split MFMA filter -> per-(lane,tile,reg)
// best-2 (u64 pack: d-bits<<32 | k, ties->lower k) -> cross-lane window
// collection -> exact sequential-fma rescue only for contested rows.
__launch_bounds__(256, 2)
__global__ void vq_main(const float* __restrict__ x, const float* __restrict__ w,
                        const float* __restrict__ ws, float* __restrict__ dout) {
#pragma clang fp contract(off)
  __shared__ unsigned short xstage[256 * 64];   // 32 KB, phase h then phase l
  __shared__ float t_lds[KK];
  __shared__ float s_lds[256];
  __shared__ int   ccnt[256];
  __shared__ unsigned short cand[256][8];
  __shared__ unsigned char flags[KK];

  const float* tvec = ws + WS_TVEC;
  const s16x8* wph8 = (const s16x8*)(ws + WS_WPH);
  const s16x8* wpl8 = (const s16x8*)(ws + WS_WPL);
  int* hist = (int*)ws + WS_HIST;
  float* lacc = (float*)ws + WS_LACC;

  const int tid  = threadIdx.x;
  const int lane = tid & 63;
  const int wv   = tid >> 6;

  for (int e = tid; e < KK; e += 256) { t_lds[e] = tvec[e]; flags[e] = 0; }
  ccnt[tid] = 0;

  const int n = blockIdx.x * 256 + tid;
  const int b = n >> 13, l = n & 8191;
  const float* px = x + (size_t)b * DD * LL + l;

  float xr[64];
#pragma unroll
  for (int i = 0; i < 64; i++) xr[i] = px[(size_t)i * LL];

  // s = ||x||^2, np-pairwise(unroll-8) order — exact, reused by rescue path
  float s;
  {
    float r[8];
#pragma unroll
    for (int j = 0; j < 8; j++) r[j] = xr[j] * xr[j];
#pragma unroll
    for (int blk = 8; blk < 64; blk += 8) {
#pragma unroll
      for (int j = 0; j < 8; j++) { float a = xr[blk + j] * xr[blk + j]; r[j] = r[j] + a; }
    }
    s = ((r[0] + r[1]) + (r[2] + r[3])) + ((r[4] + r[5]) + (r[6] + r[7]));
  }
  s_lds[tid] = s;

  // phase 1: stage xh (bf16 hi) row-major [row][d]
  {
    unsigned int* xs32 = (unsigned int*)xstage;
#pragma unroll
    for (int j = 0; j < 32; j++) {
      unsigned int v = (unsigned int)f2bf(xr[2 * j]) | ((unsigned int)f2bf(xr[2 * j + 1]) << 16);
      xs32[tid * 32 + j] = v;
    }
  }
  __syncthreads();   // covers t_lds, flags, ccnt, s_lds, xstage(h)

  // A-fragments, hi: tile tl row = wv*64+tl*16+(lane&15); k = ks*32 + 8*(lane>>4)+j
  s16x8 afh[4][2], afl[4][2];
  {
    const s16x8* xs8 = (const s16x8*)xstage;
#pragma unroll
    for (int tl = 0; tl < 4; tl++)
#pragma unroll
      for (int ks = 0; ks < 2; ks++)
        afh[tl][ks] = xs8[(wv * 64 + tl * 16 + (lane & 15)) * 8 + ks * 4 + (lane >> 4)];
  }
  __syncthreads();   // frags read before overwrite

  // phase 2: stage xl (bf16 lo of residual)
  {
    unsigned int* xs32 = (unsigned int*)xstage;
#pragma unroll
    for (int j = 0; j < 32; j++) {
      float v0 = xr[2 * j],     h0 = bf2f(f2bf(v0));
      float v1 = xr[2 * j + 1], h1 = bf2f(f2bf(v1));
      unsigned int v = (unsigned int)f2bf(v0 - h0) | ((unsigned int)f2bf(v1 - h1) << 16);
      xs32[tid * 32 + j] = v;
    }
  }
  __syncthreads();
  {
    const s16x8* xs8 = (const s16x8*)xstage;
#pragma unroll
    for (int tl = 0; tl < 4; tl++)
#pragma unroll
      for (int ks = 0; ks < 2; ks++)
        afl[tl][ks] = xs8[(wv * 64 + tl * 16 + (lane & 15)) * 8 + ks * 4 + (lane >> 4)];
  }

  // s-fragments: acc row = (lane>>4)*4 + r within tile
  float sfr[4][4];
#pragma unroll
  for (int tl = 0; tl < 4; tl++)
#pragma unroll
    for (int r = 0; r < 4; r++)
      sfr[tl][r] = s_lds[wv * 64 + tl * 16 + ((lane >> 4) << 2) + r];

  unsigned long long t1[4][4], t2[4][4];
#pragma unroll
  for (int tl = 0; tl < 4; tl++)
#pragma unroll
    for (int r = 0; r < 4; r++) { t1[tl][r] = ~0ULL; t2[tl][r] = ~0ULL; }

#pragma clang loop unroll(disable)
  for (int ct = 0; ct < 32; ct++) {
    s16x8 bh0 = wph8[(ct * 2 + 0) * 64 + lane];
    s16x8 bh1 = wph8[(ct * 2 + 1) * 64 + lane];
    s16x8 bl0 = wpl8[(ct * 2 + 0) * 64 + lane];
    s16x8 bl1 = wpl8[(ct * 2 + 1) * 64 + lane];
    float tc = t_lds[ct * 16 + (lane & 15)];
    unsigned long long klo = (unsigned long long)(ct * 16 + (lane & 15));

#pragma unroll
    for (int tl = 0; tl < 4; tl++) {
      f32x4 acc = {0.f, 0.f, 0.f, 0.f};
      acc = __builtin_amdgcn_mfma_f32_16x16x32_bf16(afl[tl][0], bh0, acc, 0, 0, 0);
      acc = __builtin_amdgcn_mfma_f32_16x16x32_bf16(afl[tl][1], bh1, acc, 0, 0, 0);
      acc = __builtin_amdgcn_mfma_f32_16x16x32_bf16(afh[tl][0], bl0, acc, 0, 0, 0);
      acc = __builtin_amdgcn_mfma_f32_16x16x32_bf16(afh[tl][1], bl1, acc, 0, 0, 0);
      acc = __builtin_amdgcn_mfma_f32_16x16x32_bf16(afh[tl][0], bh0, acc, 0, 0, 0);
      acc = __builtin_amdgcn_mfma_f32_16x16x32_bf16(afh[tl][1], bh1, acc, 0, 0, 0);
#pragma unroll
      for (int r = 0; r < 4; r++) {
        float dap = fmaf(-2.0f, acc[r], sfr[tl][r] + tc);
        unsigned long long pk = (((unsigned long long)__float_as_uint(dap)) << 32) | klo;
        bool c1 = pk < t1[tl][r];
        bool c2 = pk < t2[tl][r];
        t2[tl][r] = c1 ? t1[tl][r] : (c2 ? pk : t2[tl][r]);
        t1[tl][r] = c1 ? pk : t1[tl][r];
      }
    }
  }

  // cross-lane global min per row (butterfly over lane&15 on a copy of t1)
  unsigned long long g[4][4];
#pragma unroll
  for (int tl = 0; tl < 4; tl++)
#pragma unroll
    for (int r = 0; r < 4; r++) g[tl][r] = t1[tl][r];
#pragma unroll
  for (int m = 1; m <= 8; m <<= 1) {
#pragma unroll
    for (int tl = 0; tl < 4; tl++)
#pragma unroll
      for (int r = 0; r < 4; r++) {
        unsigned long long q = __shfl_xor(g[tl][r], m);
        g[tl][r] = q < g[tl][r] ? q : g[tl][r];
      }
  }

  // window collection: each lane appends its subset's in-window entries.
  // If BOTH entries of a subset are in-window, the subset may be truncated ->
  // append marker 512+residue: owner rescans that whole 32-code subset.
#pragma unroll
  for (int tl = 0; tl < 4; tl++)
#pragma unroll
    for (int r = 0; r < 4; r++) {
      int row = wv * 64 + tl * 16 + ((lane >> 4) << 2) + r;
      float thr = __uint_as_float((unsigned int)(g[tl][r] >> 32)) + WINDOW;
      float m1 = __uint_as_float((unsigned int)(t1[tl][r] >> 32));
      float m2 = __uint_as_float((unsigned int)(t2[tl][r] >> 32));
      bool in1 = (m1 <= thr), in2 = (m2 <= thr);
      if (in1) { int p = atomicAdd(&ccnt[row], 1); if (p < 8) cand[row][p] = (unsigned short)(t1[tl][r] & 0xFFFFu); }
      if (in2) { int p = atomicAdd(&ccnt[row], 1); if (p < 8) cand[row][p] = (unsigned short)(t2[tl][r] & 0xFFFFu); }
      if (in1 && in2) { int p = atomicAdd(&ccnt[row], 1); if (p < 8) cand[row][p] = (unsigned short)(512 + (lane & 15)); }
    }
  __syncthreads();

  // owner decision: 1 candidate -> done; else exact bit-matching rescue
  int kwin;
  {
    int cnt = ccnt[tid];
    if (cnt == 1) {
      kwin = cand[tid][0];
    } else {
      unsigned long long best = ~0ULL;
      auto evalExact = [&](int c) {
        const float4* wr = (const float4*)(w + c * DD);
        float gg = 0.0f;
#pragma unroll
        for (int i = 0; i < 16; i++) {
          float4 wq = wr[i];
          gg = fmaf(xr[4 * i + 0], wq.x, gg); gg = fmaf(xr[4 * i + 1], wq.y, gg);
          gg = fmaf(xr[4 * i + 2], wq.z, gg); gg = fmaf(xr[4 * i + 3], wq.w, gg);
        }
        float de = fmaf(-2.0f, gg, s + t_lds[c]);   // bit-identical to ref chain
        unsigned long long pk = (((unsigned long long)__float_as_uint(de)) << 32) | (unsigned long long)c;
        if (pk < best) best = pk;
      };
      if (cnt > 8) {
        for (int c = 0; c < KK; c++) evalExact(c);
      } else {
        for (int i = 0; i < cnt; i++) {
          int c = cand[tid][i];
          if (c < 512) evalExact(c);
          else { int c0 = c - 512; for (int jj = 0; jj < 32; jj++) evalExact(jj * 16 + c0); }
        }
      }
      kwin = (int)(best & 0xFFFFu);
    }
  }

  // epilogue: quantized output (transposed back), loss partial, idx, flags
  float ls = 0.0f;
  {
    float* o = dout + (size_t)b * DD * LL + l;
    const float4* wr = (const float4*)(w + kwin * DD);
#pragma unroll
    for (int i = 0; i < 16; i++) {
      float4 v = wr[i];
      o[(size_t)(4 * i + 0) * LL] = v.x; o[(size_t)(4 * i + 1) * LL] = v.y;
      o[(size_t)(4 * i + 2) * LL] = v.z; o[(size_t)(4 * i + 3) * LL] = v.w;
      float df;
      df = v.x - xr[4 * i + 0]; ls = fmaf(df, df, ls);
      df = v.y - xr[4 * i + 1]; ls = fmaf(df, df, ls);
      df = v.z - xr[4 * i + 2]; ls = fmaf(df, df, ls);
      df = v.w - xr[4 * i + 3]; ls = fmaf(df, df, ls);
    }
  }
  dout[IDX_OFF + n] = (float)kwin;

  // loss: wave reduce then one atomic per wave (order-insensitive at tolerance)
#pragma unroll
  for (int o = 32; o > 0; o >>= 1) ls += __shfl_down(ls, o);
  if ((tid & 63) == 0) atomicAdd(lacc, ls);

  // perplexity histogram: LDS filter then <=512 global atomics per block
  flags[kwin] = 1;
  __syncthreads();
  for (int e = tid; e < KK; e += 256)
    if (flags[e]) atomicOr(&hist[e], 1);
}

// -----------------------------------------------------------------------------
// final: perplexity count, loss scalar, weight passthrough
__global__ void vq_final(const float* __restrict__ w, const float* __restrict__ ws,
                         float* __restrict__ dout) {
  __shared__ int red[512];
  const int* hist = (const int*)ws + WS_HIST;
  int tid = threadIdx.x;
  red[tid] = (hist[tid] != 0) ? 1 : 0;
  __syncthreads();
  for (int sx = 256; sx > 0; sx >>= 1) {
    if (tid < sx) red[tid] += red[tid + sx];
    __syncthreads();
  }
  if (tid == 0) {
    dout[PERP_OFF] = (float)red[0];
    float m = ws[WS_LACC] / 16777216.0f;
    dout[LOSS_OFF] = m + 0.1f * m;   // q + 0.1*e with q==e numerically
  }
  const float2* w2 = (const float2*)w;
  float2* o2 = (float2*)(dout + W_OFF);
  for (int j = tid; j < KK * DD / 2; j += 512) o2[j] = w2[j];
}

extern "C" void kernel_launch(void* const* d_in, const int* in_sizes, int n_in,
                              void* d_out, int out_size, void* d_ws, size_t ws_size,
                              hipStream_t stream) {
  const float* x = (const float*)d_in[0];
  const float* w = (const float*)d_in[1];
  float* dout = (float*)d_out;
  float* ws = (float*)d_ws;

  vq_init<<<128, 256, 0, stream>>>(w, ws);
  vq_main<<<NN / 256, 256, 0, stream>>>(x, w, ws, dout);
  vq_final<<<1, 512, 0, stream>>>(w, ws, dout);
}